// Round 8
// baseline (23.401 us; speedup 1.0000x reference)
//
#include <hip/hip_runtime.h>

#define NQ 11
#define NC 3
#define NANG (NC * 66)
#define BLOCK 512

typedef float f2 __attribute__((ext_vector_type(2)));

__device__ __forceinline__ f2 bc(float v) { return f2{v, v}; }
__device__ __forceinline__ f2 swp(f2 v) { return __builtin_shufflevector(v, v, 1, 0); }

// DPP quad_perm: 0xB1 = xor1, 0x4E = xor2
template<int CTRL>
__device__ __forceinline__ float dppx(float v) {
  return __int_as_float(__builtin_amdgcn_update_dpp(
      0, __float_as_int(v), CTRL, 0xF, 0xF, false));
}
template<int CTRL>
__device__ __forceinline__ f2 dpp2(f2 v) {
  f2 r; r.x = dppx<CTRL>(v.x); r.y = dppx<CTRL>(v.y); return r;
}
__device__ __forceinline__ f2 shfl2(f2 v, int m) {
  f2 r; r.x = __shfl_xor(v.x, m, 64); r.y = __shfl_xor(v.y, m, 64); return r;
}
// gfx950 permlane swaps (VALU pipe)
__device__ __forceinline__ float plp16(float v, int lane) {
  auto r = __builtin_amdgcn_permlane16_swap(__float_as_int(v), __float_as_int(v), false, false);
  return __int_as_float((lane & 16) ? r[0] : r[1]);
}
__device__ __forceinline__ float plp32(float v, int lane) {
  auto r = __builtin_amdgcn_permlane32_swap(__float_as_int(v), __float_as_int(v), false, false);
  return __int_as_float((lane & 32) ? r[0] : r[1]);
}
__device__ __forceinline__ f2 plp16_2(f2 v, int lane) {
  f2 r; r.x = plp16(v.x, lane); r.y = plp16(v.y, lane); return r;
}
__device__ __forceinline__ f2 plp32_2(f2 v, int lane) {
  f2 r; r.x = plp32(v.x, lane); r.y = plp32(v.y, lane); return r;
}
__device__ __forceinline__ float plsum16(float v) {
  auto r = __builtin_amdgcn_permlane16_swap(__float_as_int(v), __float_as_int(v), false, false);
  return __int_as_float(r[0]) + __int_as_float(r[1]);
}
__device__ __forceinline__ float plsum32(float v) {
  auto r = __builtin_amdgcn_permlane32_swap(__float_as_int(v), __float_as_int(v), false, false);
  return __int_as_float(r[0]) + __int_as_float(r[1]);
}

// ---- planar SU(2) row apply: own (r,i), partner (pr,pi), scalar coefs ----
// row0 (hi=0): new = a*own + b*partner ; row1 (hi=1): new = conj(a)*own - conj(b)*partner
// unified: new_r = ar*r - ai2*i + br2*pr - bi*pi ; new_i = ar*i + ai2*r + br2*pi + bi*pr
// with ai2 = hi?-ai:+ai, br2 = hi?-br:+br.
__device__ __forceinline__ void prow(f2& r, f2& i, f2 pr, f2 pi,
                                     float ar, float ai2, float br2, float bi) {
  const f2 nr = bc(ar)*r - bc(ai2)*i + bc(br2)*pr - bc(bi)*pi;
  const f2 ni = bc(ar)*i + bc(ai2)*r + bc(br2)*pi + bc(bi)*pr;
  r = nr; i = ni;
}
__device__ __forceinline__ void gcross(f2& r, f2& i, f2 pr, f2 pi, float4 U, bool hi) {
  prow(r, i, pr, pi, U.x, hi ? -U.y : U.y, hi ? -U.z : U.z, U.w);
}

// wave-bit gate via LDS exchange (planar: 4 f2 per thread)
template<int WVX>
__device__ __forceinline__ void g_wave(f2& Ar, f2& Ai, f2& Br, f2& Bi, float4 U,
                                       f2* __restrict__ buf, int wave, int lane) {
  const int base = (wave << 6) | lane;
  buf[base] = Ar; buf[512 + base] = Ai; buf[1024 + base] = Br; buf[1536 + base] = Bi;
  __syncthreads();
  const int pb = ((wave ^ WVX) << 6) | lane;
  const bool hi = (wave & WVX) != 0;
  gcross(Ar, Ai, buf[pb],        buf[512 + pb],  U, hi);
  gcross(Br, Bi, buf[1024 + pb], buf[1536 + pb], U, hi);
}

__global__ __launch_bounds__(BLOCK) void qsim_kernel(
    const float* __restrict__ x, const float* __restrict__ W,
    const float* __restrict__ bias, float* __restrict__ out) {
  const int bidx = blockIdx.x;
  const int tid = threadIdx.x;
  const int lane = tid & 63, wave = tid >> 6;   // wave 0..7

  __shared__ float xs[NQ];
  __shared__ float ang[NANG];
  __shared__ float4 m1s[NC * NQ];   // fused 1q matrices (SU2: a,b)
  __shared__ float4 m2s[NC * NQ];   // fused controlled matrices
  __shared__ float4 v1s[NC * 10];   // V[t] = m2[t-1] * m1[t], t=1..10
  __shared__ f2 ex0[2048];
  __shared__ f2 ex1[2048];
  __shared__ float red[8][24];

  if (tid < NQ) xs[tid] = x[bidx * NQ + tid];
  __syncthreads();

  if (tid < NANG) {
    const int c = tid / 66, o = tid - c * 66;
    const float* wr = W + (c * 66 + o) * NQ;
    float s = bias[c * 66 + o];
#pragma unroll
    for (int i = 0; i < NQ; ++i) s += wr[i] * xs[i];
    ang[tid] = s;
  }
  __syncthreads();

  if (tid < 2 * NC * NQ) {
    const int kind = tid / (NC * NQ);
    const int id = tid - kind * (NC * NQ);
    const int c = id / NQ, q = id - c * NQ;
    const float* a = ang + c * 66;
    if (kind == 0) {
      // U = RZ(a3) RY(a2) RZ(a1) RY(a0), SU2 form (a,b)
      float s0,c0,s1,c1,s2,c2,s3,c3;
      sincosf(0.5f*a[q],      &s0,&c0);
      sincosf(0.5f*a[11+q],   &s1,&c1);
      sincosf(0.5f*a[22+q],   &s2,&c2);
      sincosf(0.5f*a[33+q],   &s3,&c3);
      const float mar = c1*c0, mai = -s1*c0;
      const float mbr = -c1*s0, mbi = s1*s0;
      const float nar = c2*mar + s2*mbr, nai = c2*mai - s2*mbi;
      const float nbr = c2*mbr - s2*mar, nbi = c2*mbi + s2*mai;
      m1s[id] = make_float4(c3*nar + s3*nai, c3*nai - s3*nar,
                            c3*nbr + s3*nbi, c3*nbi - s3*nbr);
    } else {
      // U = RZ(a5) RY(a4)
      float s4,c4,s5,c5;
      sincosf(0.5f*a[44+q], &s4,&c4);
      sincosf(0.5f*a[55+q], &s5,&c5);
      m2s[id] = make_float4(c5*c4, -s5*c4, -c5*s4, s5*s4);
    }
  }
  __syncthreads();

  // V[c][t] = m2[c][t-1] * m1[c][t]  (SU2 product)
  if (tid < NC * 10) {
    const int c = tid / 10, tt = tid - c * 10, t = tt + 1;
    const float4 A = m2s[c*NQ + t - 1];
    const float4 B = m1s[c*NQ + t];
    const float pr_=A.x, pi_=A.y, qr_=A.z, qi_=A.w;
    const float ar_=B.x, ai_=B.y, br_=B.z, bi_=B.w;
    v1s[c*10 + tt] = make_float4(
      (pr_*ar_ - pi_*ai_) - (qr_*br_ + qi_*bi_),
      (pr_*ai_ + pi_*ar_) - (qi_*br_ - qr_*bi_),
      (pr_*br_ - pi_*bi_) + (qr_*ar_ + qi_*ai_),
      (pr_*bi_ + pi_*br_) + (qi_*ar_ - qr_*ai_));
  }
  __syncthreads();

  // amp bits: b0<->q0 = PACK (A: b0=0 -> amps{0,2}, B: b0=1 -> {1,3});
  // b1<->q10 = ELEMENT (x: b1=0, y: b1=1).
  // lane bits 0..5 <-> q9,q8,q7,q3,q2,q1 ; wave bits 0..2 <-> q6,q5,q4.
  f2 Ar = {0,0}, Ai = {0,0}, Br = {0,0}, Bi = {0,0};
  if (tid == 0) Ar.x = 1.f;

  int par = 0;
  for (int c = 0; c < NC; ++c) {
    const float4* M1 = &m1s[c * NQ];
    const float4* VF = &v1s[c * 10];
    { // e0: 1q(q0) = pack bit; A gets row0, B row1, cross-pack elementwise
      const float4 U = M1[0];
      const f2 oAr = Ar, oAi = Ai;
      prow(Ar, Ai, Br, Bi,  U.x,  U.y,  U.z, U.w);   // row0
      prow(Br, Bi, oAr, oAi, U.x, -U.y, -U.z, U.w);  // row1
    }
    { // e1: F(1|0): target q1 (lane b5), ctrl q0 = pack -> per-pack U
      const float4 U0 = M1[1], U1 = VF[0];
      const bool hi = (lane & 32) != 0;
      gcross(Ar, Ai, plp32_2(Ar,lane), plp32_2(Ai,lane), U0, hi);
      gcross(Br, Bi, plp32_2(Br,lane), plp32_2(Bi,lane), U1, hi);
    }
    { // e2: F(2|1): target q2 (lane b4), ctrl q1 (lane b5)
      const float4 U = *((lane & 32) ? &VF[1] : &M1[2]);
      const bool hi = (lane & 16) != 0;
      gcross(Ar, Ai, plp16_2(Ar,lane), plp16_2(Ai,lane), U, hi);
      gcross(Br, Bi, plp16_2(Br,lane), plp16_2(Bi,lane), U, hi);
    }
    { // e3: F(3|2): target q3 (lane b3), ctrl q2 (lane b4)
      const float4 U = *((lane & 16) ? &VF[2] : &M1[3]);
      const bool hi = (lane & 8) != 0;
      gcross(Ar, Ai, shfl2(Ar,8), shfl2(Ai,8), U, hi);
      gcross(Br, Bi, shfl2(Br,8), shfl2(Bi,8), U, hi);
    }
    // e4: F(4|3): target q4 (wave b2), ctrl q3 (lane b3)
    g_wave<4>(Ar,Ai,Br,Bi, *((lane & 8) ? &VF[3] : &M1[4]), par ? ex1 : ex0, wave, lane); par ^= 1;
    // e5: F(5|4): target q5 (wave b1), ctrl q4 (wave b2)
    g_wave<2>(Ar,Ai,Br,Bi, *((wave & 4) ? &VF[4] : &M1[5]), par ? ex1 : ex0, wave, lane); par ^= 1;
    // e6: F(6|5): target q6 (wave b0), ctrl q5 (wave b1)
    g_wave<1>(Ar,Ai,Br,Bi, *((wave & 2) ? &VF[5] : &M1[6]), par ? ex1 : ex0, wave, lane); par ^= 1;
    { // e7: F(7|6): target q7 (lane b2), ctrl q6 (wave b0)
      const float4 U = *((wave & 1) ? &VF[6] : &M1[7]);
      const bool hi = (lane & 4) != 0;
      gcross(Ar, Ai, shfl2(Ar,4), shfl2(Ai,4), U, hi);
      gcross(Br, Bi, shfl2(Br,4), shfl2(Bi,4), U, hi);
    }
    { // e8: F(8|7): target q8 (lane b1), ctrl q7 (lane b2)
      const float4 U = *((lane & 4) ? &VF[7] : &M1[8]);
      const bool hi = (lane & 2) != 0;
      gcross(Ar, Ai, dpp2<0x4E>(Ar), dpp2<0x4E>(Ai), U, hi);
      gcross(Br, Bi, dpp2<0x4E>(Br), dpp2<0x4E>(Bi), U, hi);
    }
    { // e9: F(9|8): target q9 (lane b0), ctrl q8 (lane b1)
      const float4 U = *((lane & 2) ? &VF[8] : &M1[9]);
      const bool hi = (lane & 1) != 0;
      gcross(Ar, Ai, dpp2<0xB1>(Ar), dpp2<0xB1>(Ai), U, hi);
      gcross(Br, Bi, dpp2<0xB1>(Br), dpp2<0xB1>(Bi), U, hi);
    }
    { // e10: F(10|9): target q10 = element bit (within-pack swap), ctrl q9 (lane b0)
      const float4 U = *((lane & 1) ? &VF[9] : &M1[10]);
      const f2 vai = f2{-U.y, U.y};
      const f2 vbr = f2{U.z, -U.z};
      {
        const f2 sr = swp(Ar), si = swp(Ai);
        const f2 nr = bc(U.x)*Ar + vai*Ai + vbr*sr - bc(U.w)*si;
        const f2 ni = bc(U.x)*Ai - vai*Ar + vbr*si + bc(U.w)*sr;
        Ar = nr; Ai = ni;
      }
      {
        const f2 sr = swp(Br), si = swp(Bi);
        const f2 nr = bc(U.x)*Br + vai*Bi + vbr*sr - bc(U.w)*si;
        const f2 ni = bc(U.x)*Bi - vai*Br + vbr*si + bc(U.w)*sr;
        Br = nr; Bi = ni;
      }
    }
    { // e11: C(10->0): ctrl q10 = element y, target q0 = pack -> masked cross
      const float4 U = m2s[c * NQ + 10];
      const f2 ma  = f2{1.f, U.x};
      const f2 mai = f2{0.f, U.y};
      const f2 mbr = f2{0.f, U.z};
      const f2 mbi = f2{0.f, U.w};
      const f2 oAr = Ar, oAi = Ai;
      const f2 nAr = ma*Ar - mai*Ai + mbr*Br - mbi*Bi;
      const f2 nAi = ma*Ai + mai*Ar + mbr*Bi + mbi*Br;
      const f2 nBr = ma*Br + mai*Bi - mbr*oAr - mbi*oAi;
      const f2 nBi = ma*Bi - mai*Br - mbr*oAi + mbi*oAr;
      Ar = nAr; Ai = nAi; Br = nBr; Bi = nBi;
    }
  }

  // ---- expectations ----
  f2* eb = par ? ex1 : ex0;
  const int base = (wave << 6) | lane;
  eb[base] = Ar; eb[512 + base] = Ai; eb[1024 + base] = Br; eb[1536 + base] = Bi;
  __syncthreads();
  const int pb4 = ((wave ^ 4) << 6) | lane;
  const int pb2 = ((wave ^ 2) << 6) | lane;
  const int pb1 = ((wave ^ 1) << 6) | lane;
  f2 t;
  t = Ar*eb[pb4] + Ai*eb[512+pb4] + Br*eb[1024+pb4] + Bi*eb[1536+pb4];
  const float xq4 = t.x + t.y;
  t = Ar*eb[pb2] + Ai*eb[512+pb2] + Br*eb[1024+pb2] + Bi*eb[1536+pb2];
  const float xq5 = t.x + t.y;
  t = Ar*eb[pb1] + Ai*eb[512+pb1] + Br*eb[1024+pb1] + Bi*eb[1536+pb1];
  const float xq6 = t.x + t.y;

  const f2 mgA = Ar*Ar + Ai*Ai;
  const f2 mgB = Br*Br + Bi*Bi;
  const f2 mgS = mgA + mgB;
  const float ztot = mgS.x + mgS.y;
  const float zq0  = (mgA.x + mgA.y) - (mgB.x + mgB.y);
  const float zq10 = mgS.x - mgS.y;
  t = Ar*Br + Ai*Bi;
  const float xq0 = 2.f * (t.x + t.y);
  t = Ar*swp(Ar) + Ai*swp(Ai) + Br*swp(Br) + Bi*swp(Bi);
  const float xq10 = t.x + t.y;
  t = Ar*dpp2<0xB1>(Ar) + Ai*dpp2<0xB1>(Ai) + Br*dpp2<0xB1>(Br) + Bi*dpp2<0xB1>(Bi);
  const float xq9 = t.x + t.y;
  t = Ar*dpp2<0x4E>(Ar) + Ai*dpp2<0x4E>(Ai) + Br*dpp2<0x4E>(Br) + Bi*dpp2<0x4E>(Bi);
  const float xq8 = t.x + t.y;
  t = Ar*shfl2(Ar,4) + Ai*shfl2(Ai,4) + Br*shfl2(Br,4) + Bi*shfl2(Bi,4);
  const float xq7 = t.x + t.y;
  t = Ar*shfl2(Ar,8) + Ai*shfl2(Ai,8) + Br*shfl2(Br,8) + Bi*shfl2(Bi,8);
  const float xq3 = t.x + t.y;
  t = Ar*plp16_2(Ar,lane) + Ai*plp16_2(Ai,lane) + Br*plp16_2(Br,lane) + Bi*plp16_2(Bi,lane);
  const float xq2 = t.x + t.y;
  t = Ar*plp32_2(Ar,lane) + Ai*plp32_2(Ai,lane) + Br*plp32_2(Br,lane) + Bi*plp32_2(Bi,lane);
  const float xq1 = t.x + t.y;

  float v[22];
  v[0]=xq0; v[1]=xq1; v[2]=xq2; v[3]=xq3; v[4]=xq4; v[5]=xq5; v[6]=xq6;
  v[7]=xq7; v[8]=xq8; v[9]=xq9; v[10]=xq10;
  v[11] = zq0;
  v[12] = (lane & 32) ? -ztot : ztot;   // Z q1
  v[13] = (lane & 16) ? -ztot : ztot;   // Z q2
  v[14] = (lane & 8)  ? -ztot : ztot;   // Z q3
  v[15] = (wave & 4)  ? -ztot : ztot;   // Z q4
  v[16] = (wave & 2)  ? -ztot : ztot;   // Z q5
  v[17] = (wave & 1)  ? -ztot : ztot;   // Z q6
  v[18] = (lane & 4)  ? -ztot : ztot;   // Z q7
  v[19] = (lane & 2)  ? -ztot : ztot;   // Z q8
  v[20] = (lane & 1)  ? -ztot : ztot;   // Z q9
  v[21] = zq10;

  // reduction: DPP quad levels, pack 4/reg, shfl xor4/8, permlane 16/32
#pragma unroll
  for (int k = 0; k < 22; ++k) {
    v[k] += dppx<0xB1>(v[k]);
    v[k] += dppx<0x4E>(v[k]);
  }
  const int q4l = lane & 3;
  float wv[6];
#pragma unroll
  for (int p = 0; p < 5; ++p)
    wv[p] = q4l == 0 ? v[4*p] : (q4l == 1 ? v[4*p+1] : (q4l == 2 ? v[4*p+2] : v[4*p+3]));
  wv[5] = q4l == 0 ? v[20] : (q4l == 1 ? v[21] : 0.f);
#pragma unroll
  for (int p = 0; p < 6; ++p) {
    wv[p] += __shfl_xor(wv[p], 4, 64);
    wv[p] += __shfl_xor(wv[p], 8, 64);
    wv[p] = plsum16(wv[p]);
    wv[p] = plsum32(wv[p]);
  }
  if (lane < 4) {
#pragma unroll
    for (int p = 0; p < 6; ++p) red[wave][4*p + lane] = wv[p];
  }
  __syncthreads();
  if (tid < 22) {
    float sacc = 0.f;
#pragma unroll
    for (int w8 = 0; w8 < 8; ++w8) sacc += red[w8][tid];
    out[bidx * 22 + tid] = sacc;
  }
}

extern "C" void kernel_launch(void* const* d_in, const int* in_sizes, int n_in,
                              void* d_out, int out_size, void* d_ws, size_t ws_size,
                              hipStream_t stream) {
  (void)n_in; (void)d_ws; (void)ws_size; (void)out_size;
  const float* x = (const float*)d_in[0];
  const float* W = (const float*)d_in[1];
  const float* b = (const float*)d_in[2];
  float* out = (float*)d_out;
  const int batch = in_sizes[0] / NQ;
  qsim_kernel<<<batch, BLOCK, 0, stream>>>(x, W, b, out);
}

// Round 9
// 21.346 us; speedup vs baseline: 1.0963x; 1.0963x over previous
//
#include <hip/hip_runtime.h>

#define NQ 11
#define NC 3
#define NANG (NC * 66)
#define BLOCK 512

typedef float f2 __attribute__((ext_vector_type(2)));

__device__ __forceinline__ f2 swp(f2 v) { return __builtin_shufflevector(v, v, 1, 0); }

// DPP quad_perm: 0xB1 = xor1, 0x4E = xor2
template<int CTRL>
__device__ __forceinline__ float dppx(float v) {
  return __int_as_float(__builtin_amdgcn_update_dpp(
      0, __float_as_int(v), CTRL, 0xF, 0xF, false));
}
template<int CTRL>
__device__ __forceinline__ f2 dpp2(f2 v) {
  f2 r; r.x = dppx<CTRL>(v.x); r.y = dppx<CTRL>(v.y); return r;
}
// ds_swizzle BitMode xor patterns: xor4 = 0x101F, xor8 = 0x201F
template<int OFF>
__device__ __forceinline__ float swz1(float v) {
  return __int_as_float(__builtin_amdgcn_ds_swizzle(__float_as_int(v), OFF));
}
template<int OFF>
__device__ __forceinline__ f2 swz2(f2 v) {
  f2 r; r.x = swz1<OFF>(v.x); r.y = swz1<OFF>(v.y); return r;
}
// gfx950 permlane swaps (VALU pipe)
__device__ __forceinline__ float plp16(float v, int lane) {
  auto r = __builtin_amdgcn_permlane16_swap(__float_as_int(v), __float_as_int(v), false, false);
  return __int_as_float((lane & 16) ? r[0] : r[1]);
}
__device__ __forceinline__ float plp32(float v, int lane) {
  auto r = __builtin_amdgcn_permlane32_swap(__float_as_int(v), __float_as_int(v), false, false);
  return __int_as_float((lane & 32) ? r[0] : r[1]);
}
__device__ __forceinline__ f2 plp16_2(f2 v, int lane) {
  f2 r; r.x = plp16(v.x, lane); r.y = plp16(v.y, lane); return r;
}
__device__ __forceinline__ f2 plp32_2(f2 v, int lane) {
  f2 r; r.x = plp32(v.x, lane); r.y = plp32(v.y, lane); return r;
}
__device__ __forceinline__ float plsum16(float v) {
  auto r = __builtin_amdgcn_permlane16_swap(__float_as_int(v), __float_as_int(v), false, false);
  return __int_as_float(r[0]) + __int_as_float(r[1]);
}
__device__ __forceinline__ float plsum32(float v) {
  auto r = __builtin_amdgcn_permlane32_swap(__float_as_int(v), __float_as_int(v), false, false);
  return __int_as_float(r[0]) + __int_as_float(r[1]);
}

// SU(2) U = [[a,b],[-conj(b),conj(a)]] as float4 (ar,ai,br,bi).
// Packed complex apply to in-thread pair: (v0,v1) <- U (v0,v1)
__device__ __forceinline__ void apply2p(f2& v0, f2& v1, float4 U) {
  const f2 ai2 = {-U.y, U.y};
  const f2 bi2 = {-U.w, U.w};
  const f2 w0 = swp(v0), w1 = swp(v1);
  const f2 n0 =  U.x * v0 + ai2 * w0 + U.z * v1 + bi2 * w1;
  const f2 n1 = -U.z * v0 + bi2 * w0 + U.x * v1 - ai2 * w1;
  v0 = n0; v1 = n1;
}
// own/partner row apply: v <- row(hi) of U applied to (own=v, partner=p)
__device__ __forceinline__ void gpartp(f2& v, f2 p, float4 U, bool hi) {
  const f2 ai2 = hi ? f2{U.y, -U.y} : f2{-U.y, U.y};
  const float br = hi ? -U.z : U.z;
  const f2 bi2 = {-U.w, U.w};
  v = U.x * v + ai2 * swp(v) + br * p + bi2 * swp(p);
}

// gate on lane bit M via ds_swizzle (OFF = matching xor pattern)
template<int OFF, int M>
__device__ __forceinline__ void g_swz(f2 (&s)[4], float4 U, int lane) {
  const bool hi = (lane & M) != 0;
#pragma unroll
  for (int i = 0; i < 4; ++i) gpartp(s[i], swz2<OFF>(s[i]), U, hi);
}
template<int CTRL, int M>
__device__ __forceinline__ void g_dpp(f2 (&s)[4], float4 U, int lane) {
  const bool hi = (lane & M) != 0;
#pragma unroll
  for (int i = 0; i < 4; ++i) gpartp(s[i], dpp2<CTRL>(s[i]), U, hi);
}
__device__ __forceinline__ void g_pl16(f2 (&s)[4], float4 U, int lane) {
  const bool hi = (lane & 16) != 0;
#pragma unroll
  for (int i = 0; i < 4; ++i) gpartp(s[i], plp16_2(s[i], lane), U, hi);
}
// target lane bit 32; matrix per amp by reg bit0
__device__ __forceinline__ void g_pl32_regsel(f2 (&s)[4], float4 U0, float4 U1, int lane) {
  const bool hi = (lane & 32) != 0;
#pragma unroll
  for (int i = 0; i < 4; ++i)
    gpartp(s[i], plp32_2(s[i], lane), (i & 1) ? U1 : U0, hi);
}
// wave-bit gate via LDS exchange
template<int WVX>
__device__ __forceinline__ void g_wave(f2 (&s)[4], float4 U, f2* buf, int wave, int lane) {
  const int base = (wave << 6) | lane;
#pragma unroll
  for (int i = 0; i < 4; ++i) buf[(i << 9) | base] = s[i];
  __syncthreads();
  const int pbase = ((wave ^ WVX) << 6) | lane;
  const bool hi = (wave & WVX) != 0;
#pragma unroll
  for (int i = 0; i < 4; ++i) gpartp(s[i], buf[(i << 9) | pbase], U, hi);
}

__global__ __launch_bounds__(BLOCK) void qsim_kernel(
    const float* __restrict__ x, const float* __restrict__ W,
    const float* __restrict__ bias, float* __restrict__ out) {
  const int bidx = blockIdx.x;
  const int tid = threadIdx.x;
  const int lane = tid & 63, wave = tid >> 6;   // wave 0..7

  __shared__ float xs[NQ];
  __shared__ float ang[NANG];
  __shared__ float4 m1s[NC * NQ];   // fused 1q matrices (SU2)
  __shared__ float4 m2s[NC * NQ];   // fused controlled matrices (SU2)
  __shared__ float4 v1s[NC * 10];   // V[t] = m2[t-1] * m1[t], t=1..10
  __shared__ f2 ex0[2048];
  __shared__ f2 ex1[2048];
  __shared__ float red[8][24];

  if (tid < NQ) xs[tid] = x[bidx * NQ + tid];
  __syncthreads();

  if (tid < NANG) {
    const int c = tid / 66, o = tid - c * 66;
    const float* wr = W + (c * 66 + o) * NQ;
    float s = bias[c * 66 + o];
#pragma unroll
    for (int i = 0; i < NQ; ++i) s += wr[i] * xs[i];
    ang[tid] = s;
  }
  __syncthreads();

  if (tid < 2 * NC * NQ) {
    const int kind = tid / (NC * NQ);
    const int id = tid - kind * (NC * NQ);
    const int c = id / NQ, q = id - c * NQ;
    const float* a = ang + c * 66;
    if (kind == 0) {
      // U = RZ(a3) RY(a2) RZ(a1) RY(a0), SU2 form (a,b)
      float s0,c0,s1,c1,s2,c2,s3,c3;
      sincosf(0.5f*a[q],      &s0,&c0);
      sincosf(0.5f*a[11+q],   &s1,&c1);
      sincosf(0.5f*a[22+q],   &s2,&c2);
      sincosf(0.5f*a[33+q],   &s3,&c3);
      const float mar = c1*c0, mai = -s1*c0;
      const float mbr = -c1*s0, mbi = s1*s0;
      const float nar = c2*mar + s2*mbr, nai = c2*mai - s2*mbi;
      const float nbr = c2*mbr - s2*mar, nbi = c2*mbi + s2*mai;
      m1s[id] = make_float4(c3*nar + s3*nai, c3*nai - s3*nar,
                            c3*nbr + s3*nbi, c3*nbi - s3*nbr);
    } else {
      // U = RZ(a5) RY(a4)
      float s4,c4,s5,c5;
      sincosf(0.5f*a[44+q], &s4,&c4);
      sincosf(0.5f*a[55+q], &s5,&c5);
      m2s[id] = make_float4(c5*c4, -s5*c4, -c5*s4, s5*s4);
    }
  }
  __syncthreads();

  // V[c][t] = m2[c][t-1] * m1[c][t]  (SU2 product)
  if (tid < NC * 10) {
    const int c = tid / 10, tt = tid - c * 10, t = tt + 1;
    const float4 A = m2s[c*NQ + t - 1];
    const float4 B = m1s[c*NQ + t];
    const float pr_=A.x, pi_=A.y, qr_=A.z, qi_=A.w;
    const float ar_=B.x, ai_=B.y, br_=B.z, bi_=B.w;
    v1s[c*10 + tt] = make_float4(
      (pr_*ar_ - pi_*ai_) - (qr_*br_ + qi_*bi_),
      (pr_*ai_ + pi_*ar_) - (qi_*br_ - qr_*bi_),
      (pr_*br_ - pi_*bi_) + (qr_*ar_ + qi_*ai_),
      (pr_*bi_ + pi_*br_) + (qi_*ar_ - qr_*ai_));
  }
  __syncthreads();

  // amp bits: [1:0]=reg (b0<->q0, b1<->q10); [7:2]=lane bits 0..5 <->
  // q9,q8,q7,q3,q2,q1 ; [10:8]=wave bits <-> q6,q5,q4
  f2 s[4];
#pragma unroll
  for (int i = 0; i < 4; ++i) s[i] = f2{0.f, 0.f};
  if (tid == 0) s[0].x = 1.f;

  int par = 0;
#pragma unroll
  for (int c = 0; c < NC; ++c) {
    const float4* M1 = &m1s[c * NQ];
    const float4* VF = &v1s[c * 10];
    // ---- preload all 13 per-circuit matrices into registers (batched ds_read) ----
    const float4 u0  = M1[0];
    const float4 u1a = M1[1];
    const float4 u1b = VF[0];
    const float4 u2  = *((lane & 32) ? &VF[1] : &M1[2]);
    const float4 u3  = *((lane & 16) ? &VF[2] : &M1[3]);
    const float4 u4  = *((lane & 8)  ? &VF[3] : &M1[4]);
    const float4 u5  = *((wave & 4)  ? &VF[4] : &M1[5]);
    const float4 u6  = *((wave & 2)  ? &VF[5] : &M1[6]);
    const float4 u7  = *((wave & 1)  ? &VF[6] : &M1[7]);
    const float4 u8  = *((lane & 4)  ? &VF[7] : &M1[8]);
    const float4 u9  = *((lane & 2)  ? &VF[8] : &M1[9]);
    const float4 u10 = *((lane & 1)  ? &VF[9] : &M1[10]);
    const float4 u11 = m2s[c * NQ + 10];

    { // e0: 1q(q0), reg bit0
      apply2p(s[0], s[1], u0);
      apply2p(s[2], s[3], u0);
    }
    g_pl32_regsel(s, u1a, u1b, lane);                               // e1: F(1|0)
    g_pl16(s, u2, lane);                                            // e2: F(2|1)
    g_swz<0x201F,8>(s, u3, lane);                                   // e3: F(3|2) xor8, hi=lane&8
    g_wave<4>(s, u4, par ? ex1 : ex0, wave, lane); par ^= 1;        // e4: F(4|3)
    g_wave<2>(s, u5, par ? ex1 : ex0, wave, lane); par ^= 1;        // e5: F(5|4)
    g_wave<1>(s, u6, par ? ex1 : ex0, wave, lane); par ^= 1;        // e6: F(6|5)
    g_swz<0x101F,4>(s, u7, lane);                                   // e7: F(7|6) xor4, hi=lane&4
    g_dpp<0x4E,2>(s, u8, lane);                                     // e8: F(8|7)
    g_dpp<0xB1,1>(s, u9, lane);                                     // e9: F(9|8)
    { // e10: F(10|9), target reg bit1, ctrl lane bit0
      apply2p(s[0], s[2], u10);
      apply2p(s[1], s[3], u10);
    }
    { // e11: C(10->0): ctrl reg bit1, target reg bit0 — pure registers
      apply2p(s[2], s[3], u11);
    }
  }

  // ---- expectations ----
  f2* eb = par ? ex1 : ex0;
  const int base = (wave << 6) | lane;
#pragma unroll
  for (int i = 0; i < 4; ++i) eb[(i << 9) | base] = s[i];
  __syncthreads();
  const int pb4 = ((wave ^ 4) << 6) | lane;
  const int pb2 = ((wave ^ 2) << 6) | lane;
  const int pb1 = ((wave ^ 1) << 6) | lane;
  f2 aq4 = {0,0}, aq5 = {0,0}, aq6 = {0,0};
#pragma unroll
  for (int i = 0; i < 4; ++i) {
    aq4 += s[i] * eb[(i << 9) | pb4];
    aq5 += s[i] * eb[(i << 9) | pb2];
    aq6 += s[i] * eb[(i << 9) | pb1];
  }
  f2 mg[4];
#pragma unroll
  for (int i = 0; i < 4; ++i) mg[i] = s[i] * s[i];
  const f2 ztv  = (mg[0] + mg[1]) + (mg[2] + mg[3]);
  const f2 z0v  = (mg[0] - mg[1]) + (mg[2] - mg[3]);
  const f2 z10v = (mg[0] + mg[1]) - (mg[2] + mg[3]);
  f2 aq0={0,0}, aq10={0,0}, aq9={0,0}, aq8={0,0}, aq7={0,0}, aq3={0,0}, aq2={0,0}, aq1={0,0};
#pragma unroll
  for (int i = 0; i < 4; ++i) {
    aq0  += s[i] * s[i ^ 1];
    aq10 += s[i] * s[i ^ 2];
    aq9  += s[i] * dpp2<0xB1>(s[i]);
    aq8  += s[i] * dpp2<0x4E>(s[i]);
    aq7  += s[i] * swz2<0x101F>(s[i]);
    aq3  += s[i] * swz2<0x201F>(s[i]);
    aq2  += s[i] * plp16_2(s[i], lane);
    aq1  += s[i] * plp32_2(s[i], lane);
  }
  const float ztot = ztv.x + ztv.y;

  float v[22];
  v[0]=aq0.x+aq0.y; v[1]=aq1.x+aq1.y; v[2]=aq2.x+aq2.y; v[3]=aq3.x+aq3.y;
  v[4]=aq4.x+aq4.y; v[5]=aq5.x+aq5.y; v[6]=aq6.x+aq6.y;
  v[7]=aq7.x+aq7.y; v[8]=aq8.x+aq8.y; v[9]=aq9.x+aq9.y; v[10]=aq10.x+aq10.y;
  v[11] = z0v.x + z0v.y;
  v[12] = (lane & 32) ? -ztot : ztot;   // Z q1
  v[13] = (lane & 16) ? -ztot : ztot;   // Z q2
  v[14] = (lane & 8)  ? -ztot : ztot;   // Z q3
  v[15] = (wave & 4)  ? -ztot : ztot;   // Z q4
  v[16] = (wave & 2)  ? -ztot : ztot;   // Z q5
  v[17] = (wave & 1)  ? -ztot : ztot;   // Z q6
  v[18] = (lane & 4)  ? -ztot : ztot;   // Z q7
  v[19] = (lane & 2)  ? -ztot : ztot;   // Z q8
  v[20] = (lane & 1)  ? -ztot : ztot;   // Z q9
  v[21] = z10v.x + z10v.y;

  // reduction: DPP quad levels, pack 4/reg, ds_swizzle xor4/8, permlane 16/32
#pragma unroll
  for (int k = 0; k < 22; ++k) {
    v[k] += dppx<0xB1>(v[k]);
    v[k] += dppx<0x4E>(v[k]);
  }
  const int q4l = lane & 3;
  float wv[6];
#pragma unroll
  for (int p = 0; p < 5; ++p)
    wv[p] = q4l == 0 ? v[4*p] : (q4l == 1 ? v[4*p+1] : (q4l == 2 ? v[4*p+2] : v[4*p+3]));
  wv[5] = q4l == 0 ? v[20] : (q4l == 1 ? v[21] : 0.f);
#pragma unroll
  for (int p = 0; p < 6; ++p) {
    wv[p] += swz1<0x101F>(wv[p]);
    wv[p] += swz1<0x201F>(wv[p]);
    wv[p] = plsum16(wv[p]);
    wv[p] = plsum32(wv[p]);
  }
  if (lane < 4) {
#pragma unroll
    for (int p = 0; p < 6; ++p) red[wave][4*p + lane] = wv[p];
  }
  __syncthreads();
  if (tid < 22) {
    float sacc = 0.f;
#pragma unroll
    for (int w8 = 0; w8 < 8; ++w8) sacc += red[w8][tid];
    out[bidx * 22 + tid] = sacc;
  }
}

extern "C" void kernel_launch(void* const* d_in, const int* in_sizes, int n_in,
                              void* d_out, int out_size, void* d_ws, size_t ws_size,
                              hipStream_t stream) {
  (void)n_in; (void)d_ws; (void)ws_size; (void)out_size;
  const float* x = (const float*)d_in[0];
  const float* W = (const float*)d_in[1];
  const float* b = (const float*)d_in[2];
  float* out = (float*)d_out;
  const int batch = in_sizes[0] / NQ;
  qsim_kernel<<<batch, BLOCK, 0, stream>>>(x, W, b, out);
}